// Round 10
// baseline (563.655 us; speedup 1.0000x reference)
//
#include <hip/hip_runtime.h>
#include <hip/hip_bf16.h>

#define N_NODES 50000
#define N_EDGES 600000
#define F 128
#define R 2
#define NLAYER 4
#define NSEG (N_NODES * R)  /* 100000 */
#define NSCB 98             /* scan blocks: ceil(100000/1024) */
#define KTOT 384            /* gemm K: 128 mm0 + 128 mm1 + 128 hbn */
#define BN_EPS 1e-5f
#define BETA 1e-4f

typedef __hip_bfloat16 bf16;
typedef __attribute__((ext_vector_type(8))) short short8;  // 8 bf16 (4 VGPRs)
typedef __attribute__((ext_vector_type(4))) float floatx4; // 4 fp32 acc

// ---------------- weight pack: Bt2[l][j][k], j=out col, k in [0,384) ----------------
// k<128: W_rel[0][k][j]; k in [128,256): W_rel[1][k-128][j]; k>=256: W_root[k-256][j]
__global__ void k_wt(const float* __restrict__ W0_rel, const float* __restrict__ W0_root,
                     const float* __restrict__ Ws_rel, const float* __restrict__ Ws_root,
                     bf16* __restrict__ Bt2) {
    int idx = blockIdx.x * 256 + threadIdx.x;
    if (idx >= NLAYER * F * KTOT) return;
    int l = idx / (F * KTOT);
    int rem = idx % (F * KTOT);
    int j = rem / KTOT, k = rem % KTOT;
    float v;
    if (k < 256) {
        int r = k >> 7, d = k & 127;
        v = (l == 0) ? W0_rel[((size_t)r * F + d) * F + j]
                     : Ws_rel[((size_t)((l - 1) * R + r) * F + d) * F + j];
    } else {
        int d = k - 256;
        v = (l == 0) ? W0_root[(size_t)d * F + j]
                     : Ws_root[((size_t)(l - 1) * F + d) * F + j];
    }
    Bt2[idx] = __float2bfloat16(v);
}

// ---------------- segment counts ----------------
__global__ void k_count(const int* __restrict__ dst, const int* __restrict__ et,
                        int* __restrict__ cnt) {
    int e = blockIdx.x * 256 + threadIdx.x;
    if (e < N_EDGES) atomicAdd(&cnt[dst[e] * R + et[e]], 1);
}

// ---------------- multi-block exclusive scan of cnt ----------------
__global__ void k_scan1(const int* __restrict__ cnt, int* __restrict__ off,
                        int* __restrict__ bsum) {
    int t = threadIdx.x;
    int g = blockIdx.x * 1024 + t;
    int v = (g < NSEG) ? cnt[g] : 0;
    int lane = t & 63;
    int wv = t >> 6;
    int x = v;
    for (int d = 1; d < 64; d <<= 1) {
        int y = __shfl_up(x, d, 64);
        if (lane >= d) x += y;
    }
    __shared__ int wtot[16];
    if (lane == 63) wtot[wv] = x;
    __syncthreads();
    if (t < 16) {
        int s = wtot[t];
        for (int d = 1; d < 16; d <<= 1) {
            int y = __shfl_up(s, d, 64);
            if (t >= d) s += y;
        }
        wtot[t] = s;
    }
    __syncthreads();
    int wpre = (wv == 0) ? 0 : wtot[wv - 1];
    int incl = x + wpre;
    if (g < NSEG) off[g] = incl - v;  // exclusive within block
    if (t == 1023) bsum[blockIdx.x] = incl;
}

__global__ void k_scan2(int* __restrict__ bsum) {
    __shared__ int s[128];
    int t = threadIdx.x;
    int v = (t < NSCB) ? bsum[t] : 0;
    s[t] = v;
    __syncthreads();
    for (int d = 1; d < 128; d <<= 1) {
        int y = (t >= d) ? s[t - d] : 0;
        __syncthreads();
        s[t] += y;
        __syncthreads();
    }
    if (t < NSCB) bsum[t] = s[t] - v;  // exclusive
}

__global__ void k_scan3(int* __restrict__ off, const int* __restrict__ bsum) {
    int g = blockIdx.x * 1024 + threadIdx.x;
    if (g < NSEG) off[g] += bsum[blockIdx.x];
}

// ---------------- fill segment-sorted src list ----------------
__global__ void k_fill(const int* __restrict__ src, const int* __restrict__ dst,
                       const int* __restrict__ et, const int* __restrict__ off,
                       int* __restrict__ fill, int* __restrict__ esrc) {
    int e = blockIdx.x * 256 + threadIdx.x;
    if (e >= N_EDGES) return;
    int seg = dst[e] * R + et[e];
    int idx = off[seg] + atomicAdd(&fill[seg], 1);
    esrc[idx] = src[e];
}

// ---------------- BN column stats: gs[0..127]=sum, gs[128..255]=sumsq ----------------
__global__ void k_bnstats(const float* __restrict__ h, float* __restrict__ gs) {
    int c = threadIdx.x & 127;
    int rl = threadIdx.x >> 7;
    float s = 0.f, q = 0.f;
    for (int r = blockIdx.x * 2 + rl; r < N_NODES; r += gridDim.x * 2) {
        float v = h[(size_t)r * F + c];
        s += v; q += v * v;
    }
    __shared__ float ls[256], lq[256];
    ls[threadIdx.x] = s; lq[threadIdx.x] = q;
    __syncthreads();
    if (rl == 0) {
        atomicAdd(&gs[c], ls[c] + ls[c + 128]);
        atomicAdd(&gs[128 + c], lq[c] + lq[c + 128]);
    }
}

// ---------------- BN apply: hbn = bf16(bn(hin)) ----------------
__global__ void k_bn(const float* __restrict__ hin, const float* __restrict__ gs,
                     bf16* __restrict__ hbn) {
    int idx = blockIdx.x * 256 + threadIdx.x;       // quad index
    if (idx >= N_NODES * F / 4) return;
    int c4 = (idx * 4) & 127;
    float4 v = *(const float4*)(hin + (size_t)idx * 4);
    bf16 o[4];
    float vv[4] = {v.x, v.y, v.z, v.w};
    #pragma unroll
    for (int c = 0; c < 4; c++) {
        float mm = gs[c4 + c] * (1.0f / N_NODES);
        float qq = gs[128 + c4 + c] * (1.0f / N_NODES);
        float rs = rsqrtf(qq - mm * mm + BN_EPS);
        o[c] = __float2bfloat16((vv[c] - mm) * rs + BETA);
    }
    *(double*)(hbn + (size_t)idx * 4) = *(const double*)o;
}

// ---------------- fused aggregate + K=384 GEMM + relu/residual ----------------
// Block = 64 nodes x 128 out cols, 512 threads (8 waves). Phase 1: each wave
// gathers per-(node,rel) means for its 8 nodes (fused relation loop over the
// contiguous esrc range; same hbn row feeds both relation accumulators via
// select-weights) -> means kept in REGISTERS. Phase 2: K=384 GEMM in 3
// chunks; As chunk 0/1 filled from mean registers, chunk 2 = own hbn rows.
// Swapped-operand MFMA (D^T) -> float4 epilogue stores, relu+residual fused.
__launch_bounds__(512)
__global__ void k_agg_gemm(const bf16* __restrict__ hbn,
                           const int* __restrict__ cnt, const int* __restrict__ off,
                           const int* __restrict__ esrc,
                           const bf16* __restrict__ Bt2, const float* __restrict__ bias,
                           float* __restrict__ h, float* __restrict__ outp, int layer) {
    __shared__ bf16 As[64 * 136];    // 17.4 KB
    __shared__ bf16 Bs[128 * 136];   // 34.8 KB
    int t = threadIdx.x;
    int m0 = blockIdx.x * 64;
    int w = t >> 6;
    int lane = t & 63;
    int f = lane * 2;
    const bf16* hb = hbn + f;
    // ---- phase 1: gather means for nodes m0 + w*8 + (0..7) ----
    __hip_bfloat162 mm0r[8], mm1r[8];
    #pragma unroll
    for (int j = 0; j < 8; j++) {
        int n = m0 + w * 8 + j;
        float a0 = 0.f, a1 = 0.f, b0 = 0.f, b1 = 0.f;
        if (n < N_NODES) {
            int2 cc = *(const int2*)(cnt + n * R);
            int c0 = cc.x, c1 = cc.y;
            int o0 = off[n * R];
            int ctot = c0 + c1;
            float inv0 = (c0 > 0) ? 1.0f / (float)c0 : 0.f;
            float inv1 = (c1 > 0) ? 1.0f / (float)c1 : 0.f;
            float sxA[4], syA[4], sxB[4], syB[4];
            #pragma unroll
            for (int k = 0; k < 4; k++) { sxA[k] = 0.f; syA[k] = 0.f; sxB[k] = 0.f; syB[k] = 0.f; }
            int i = 0;
            for (; i + 4 <= ctot; i += 4) {
                int sn[4];
                #pragma unroll
                for (int k = 0; k < 4; k++) sn[k] = esrc[o0 + i + k];
                __hip_bfloat162 p[4];
                #pragma unroll
                for (int k = 0; k < 4; k++)
                    p[k] = *(const __hip_bfloat162*)(hb + (size_t)sn[k] * F);
                #pragma unroll
                for (int k = 0; k < 4; k++) {
                    float wa = (i + k < c0) ? inv0 : 0.f;
                    float wb = (i + k < c0) ? 0.f : inv1;
                    float px = __bfloat162float(p[k].x);
                    float py = __bfloat162float(p[k].y);
                    sxA[k] = fmaf(px, wa, sxA[k]); syA[k] = fmaf(py, wa, syA[k]);
                    sxB[k] = fmaf(px, wb, sxB[k]); syB[k] = fmaf(py, wb, syB[k]);
                }
            }
            for (; i < ctot; i++) {
                int sn = esrc[o0 + i];
                __hip_bfloat162 p = *(const __hip_bfloat162*)(hb + (size_t)sn * F);
                float wa = (i < c0) ? inv0 : 0.f;
                float wb = (i < c0) ? 0.f : inv1;
                float px = __bfloat162float(p.x);
                float py = __bfloat162float(p.y);
                sxA[0] = fmaf(px, wa, sxA[0]); syA[0] = fmaf(py, wa, syA[0]);
                sxB[0] = fmaf(px, wb, sxB[0]); syB[0] = fmaf(py, wb, syB[0]);
            }
            a0 = (sxA[0] + sxA[1]) + (sxA[2] + sxA[3]);
            a1 = (syA[0] + syA[1]) + (syA[2] + syA[3]);
            b0 = (sxB[0] + sxB[1]) + (sxB[2] + sxB[3]);
            b1 = (syB[0] + syB[1]) + (syB[2] + syB[3]);
        }
        mm0r[j].x = __float2bfloat16(a0); mm0r[j].y = __float2bfloat16(a1);
        mm1r[j].x = __float2bfloat16(b0); mm1r[j].y = __float2bfloat16(b1);
    }
    // ---- phase 2: K=384 GEMM in 3 chunks ----
    int msub = w & 3;   // m-subtile 0..3
    int nh = w >> 2;    // n-half 0..1
    int lm = lane & 15;
    int lq = lane >> 4;
    int m = m0 + msub * 16 + lm;
    floatx4 acc[4];
    #pragma unroll
    for (int j = 0; j < 4; j++) acc[j] = (floatx4){0.f, 0.f, 0.f, 0.f};
    for (int ci = 0; ci < 3; ci++) {
        __syncthreads();  // previous chunk's readers done (no-op before ci=0 reads)
        // stage As chunk
        if (ci < 2) {
            #pragma unroll
            for (int j = 0; j < 8; j++) {
                int row = w * 8 + j;
                *(__hip_bfloat162*)(As + row * 136 + f) = (ci == 0) ? mm0r[j] : mm1r[j];
            }
        } else {
            for (int rr = 0; rr < 2; rr++) {
                int idx = rr * 512 + t;   // 0..1023
                int row = idx >> 4;       // 0..63
                int kc = idx & 15;        // 16B chunk
                short8 v = {0, 0, 0, 0, 0, 0, 0, 0};
                if (m0 + row < N_NODES)
                    v = *(const short8*)(hbn + (size_t)(m0 + row) * F + kc * 8);
                *(short8*)(As + row * 136 + kc * 8) = v;
            }
        }
        // stage Bs chunk: j rows 0..127, K cols [ci*128, ci*128+128)
        for (int rr = 0; rr < 4; rr++) {
            int idx = rr * 512 + t;   // 0..2047
            int row = idx >> 4;       // 0..127
            int kc = idx & 15;
            short8 v = *(const short8*)(Bt2 + (size_t)row * KTOT + ci * 128 + kc * 8);
            *(short8*)(Bs + row * 136 + kc * 8) = v;
        }
        __syncthreads();
        short8 a[4];
        #pragma unroll
        for (int ki = 0; ki < 4; ki++)
            a[ki] = *(const short8*)(As + (msub * 16 + lm) * 136 + ki * 32 + lq * 8);
        for (int tt = 0; tt < 4; tt++) {
            int nt = nh * 4 + tt;   // n-tile 0..7
            short8 b[4];
            #pragma unroll
            for (int ki = 0; ki < 4; ki++)
                b[ki] = *(const short8*)(Bs + (nt * 16 + lm) * 136 + ki * 32 + lq * 8);
            #pragma unroll
            for (int ki = 0; ki < 4; ki++)
                acc[tt] = __builtin_amdgcn_mfma_f32_16x16x32_bf16(b[ki], a[ki], acc[tt], 0, 0, 0);
        }
    }
    // epilogue: bias + relu + residual, float4 stores
    if (m < N_NODES) {
        #pragma unroll
        for (int tt = 0; tt < 4; tt++) {
            int nt = nh * 4 + tt;
            int n0 = nt * 16 + lq * 4;
            float4 bv = *(const float4*)(bias + n0);
            float4 hv = {0.f, 0.f, 0.f, 0.f};
            if (layer > 0) hv = *(const float4*)(h + (size_t)m * F + n0);
            float4 o4;
            o4.x = fmaxf(acc[tt][0] + bv.x, 0.f) + hv.x;
            o4.y = fmaxf(acc[tt][1] + bv.y, 0.f) + hv.y;
            o4.z = fmaxf(acc[tt][2] + bv.z, 0.f) + hv.z;
            o4.w = fmaxf(acc[tt][3] + bv.w, 0.f) + hv.w;
            *(float4*)(h + (size_t)m * F + n0) = o4;
            if (outp) *(float4*)(outp + (size_t)m * F + n0) = o4;
        }
    }
}

extern "C" void kernel_launch(void* const* d_in, const int* in_sizes, int n_in,
                              void* d_out, int out_size, void* d_ws, size_t ws_size,
                              hipStream_t stream) {
    const float* x       = (const float*)d_in[0];
    const int*   eidx    = (const int*)d_in[1];
    const int*   etype   = (const int*)d_in[2];
    const float* W0_rel  = (const float*)d_in[3];
    const float* W0_root = (const float*)d_in[4];
    const float* b0      = (const float*)d_in[5];
    const float* Ws_rel  = (const float*)d_in[6];
    const float* Ws_root = (const float*)d_in[7];
    const float* bs      = (const float*)d_in[8];
    const int* src = eidx;
    const int* dst = eidx + N_EDGES;

    char* w = (char*)d_ws;
    float* h   = (float*)w; w += (size_t)N_NODES * F * 4;       // 25.6 MB
    bf16*  hbn = (bf16*)w;  w += (size_t)N_NODES * F * 2;       // 12.8 MB
    bf16*  Bt2 = (bf16*)w;  w += (size_t)NLAYER * F * KTOT * 2; // 384 KB
    int* cnt   = (int*)w;   w += (size_t)NSEG * 4;              // contiguous zero region:
    int* fill  = (int*)w;   w += (size_t)NSEG * 4;              //   cnt | fill | stats
    float* stats = (float*)w; w += (size_t)NLAYER * 256 * 4;
    int* off   = (int*)w;   w += (size_t)NSEG * 4;
    int* esrc  = (int*)w;   w += (size_t)N_EDGES * 4;
    int* bsum  = (int*)w;   w += 128 * 4;                       // total ~42 MB

    hipMemsetAsync(cnt, 0, (size_t)NSEG * 4 * 2 + (size_t)NLAYER * 256 * 4, stream);
    k_wt<<<(NLAYER * F * KTOT + 255) / 256, 256, 0, stream>>>(W0_rel, W0_root, Ws_rel, Ws_root, Bt2);
    k_count<<<(N_EDGES + 255) / 256, 256, 0, stream>>>(dst, etype, cnt);
    k_scan1<<<NSCB, 1024, 0, stream>>>(cnt, off, bsum);
    k_scan2<<<1, 128, 0, stream>>>(bsum);
    k_scan3<<<NSCB, 1024, 0, stream>>>(off, bsum);
    k_fill<<<(N_EDGES + 255) / 256, 256, 0, stream>>>(src, dst, etype, off, fill, esrc);

    for (int l = 0; l < NLAYER; l++) {
        float* gs = stats + l * 256;
        const float* bias = (l == 0) ? b0 : (bs + (size_t)(l - 1) * F);
        const float* hin = (l == 0) ? x : h;
        k_bnstats<<<512, 256, 0, stream>>>(hin, gs);
        k_bn<<<(N_NODES * F / 4 + 255) / 256, 256, 0, stream>>>(hin, gs, hbn);
        k_agg_gemm<<<(N_NODES + 63) / 64, 512, 0, stream>>>(
            hbn, cnt, off, esrc, Bt2 + (size_t)l * F * KTOT, bias, h,
            (l == 3) ? (float*)d_out : nullptr, l);
    }
}

// Round 11
// 536.468 us; speedup vs baseline: 1.0507x; 1.0507x over previous
//
#include <hip/hip_runtime.h>
#include <hip/hip_bf16.h>

#define N_NODES 50000
#define N_EDGES 600000
#define F 128
#define R 2
#define NLAYER 4
#define NSEG (N_NODES * R)  /* 100000 */
#define NSCB 98             /* scan blocks: ceil(100000/1024) */
#define NB 384              /* gemm out cols: 256 y + 128 z */
#define BN_EPS 1e-5f
#define BETA 1e-4f

typedef __hip_bfloat16 bf16;
typedef __attribute__((ext_vector_type(8))) short short8;  // 8 bf16 (4 VGPRs)
typedef __attribute__((ext_vector_type(4))) float floatx4; // 4 fp32 acc

// ---------------- weight transpose + f32->bf16: Bt[l][j][d] = W[l][d][j] ----------------
// rows j: [0,128)=W_rel[0], [128,256)=W_rel[1], [256,384)=W_root; cols d = K
__global__ void k_wt(const float* __restrict__ W0_rel, const float* __restrict__ W0_root,
                     const float* __restrict__ Ws_rel, const float* __restrict__ Ws_root,
                     bf16* __restrict__ Bt) {
    int idx = blockIdx.x * 256 + threadIdx.x;
    if (idx >= NLAYER * NB * F) return;
    int l = idx / (NB * F);
    int rem = idx % (NB * F);
    int j = rem / F, d = rem % F;
    float v;
    if (j < 256) {
        int r = j >> 7, c = j & 127;
        v = (l == 0) ? W0_rel[((size_t)r * F + d) * F + c]
                     : Ws_rel[((size_t)((l - 1) * R + r) * F + d) * F + c];
    } else {
        int c = j - 256;
        v = (l == 0) ? W0_root[(size_t)d * F + c]
                     : Ws_root[((size_t)(l - 1) * F + d) * F + c];
    }
    Bt[idx] = __float2bfloat16(v);
}

// ---------------- segment counts ----------------
__global__ void k_count(const int* __restrict__ dst, const int* __restrict__ et,
                        int* __restrict__ cnt) {
    int e = blockIdx.x * 256 + threadIdx.x;
    if (e < N_EDGES) atomicAdd(&cnt[dst[e] * R + et[e]], 1);
}

// ---------------- multi-block exclusive scan of cnt ----------------
__global__ void k_scan1(const int* __restrict__ cnt, int* __restrict__ off,
                        int* __restrict__ bsum) {
    int t = threadIdx.x;
    int g = blockIdx.x * 1024 + t;
    int v = (g < NSEG) ? cnt[g] : 0;
    int lane = t & 63;
    int wv = t >> 6;
    int x = v;
    for (int d = 1; d < 64; d <<= 1) {
        int y = __shfl_up(x, d, 64);
        if (lane >= d) x += y;
    }
    __shared__ int wtot[16];
    if (lane == 63) wtot[wv] = x;
    __syncthreads();
    if (t < 16) {
        int s = wtot[t];
        for (int d = 1; d < 16; d <<= 1) {
            int y = __shfl_up(s, d, 64);
            if (t >= d) s += y;
        }
        wtot[t] = s;
    }
    __syncthreads();
    int wpre = (wv == 0) ? 0 : wtot[wv - 1];
    int incl = x + wpre;
    if (g < NSEG) off[g] = incl - v;  // exclusive within block
    if (t == 1023) bsum[blockIdx.x] = incl;
}

__global__ void k_scan2(int* __restrict__ bsum) {
    __shared__ int s[128];
    int t = threadIdx.x;
    int v = (t < NSCB) ? bsum[t] : 0;
    s[t] = v;
    __syncthreads();
    for (int d = 1; d < 128; d <<= 1) {
        int y = (t >= d) ? s[t - d] : 0;
        __syncthreads();
        s[t] += y;
        __syncthreads();
    }
    if (t < NSCB) bsum[t] = s[t] - v;  // exclusive
}

__global__ void k_scan3(int* __restrict__ off, const int* __restrict__ bsum) {
    int g = blockIdx.x * 1024 + threadIdx.x;
    if (g < NSEG) off[g] += bsum[blockIdx.x];
}

// ---------------- fill segment-sorted src list ----------------
__global__ void k_fill(const int* __restrict__ src, const int* __restrict__ dst,
                       const int* __restrict__ et, const int* __restrict__ off,
                       int* __restrict__ fill, int* __restrict__ esrc) {
    int e = blockIdx.x * 256 + threadIdx.x;
    if (e >= N_EDGES) return;
    int seg = dst[e] * R + et[e];
    int idx = off[seg] + atomicAdd(&fill[seg], 1);
    esrc[idx] = src[e];
}

// ---------------- BN column stats: gs[0..127]=sum, gs[128..255]=sumsq ----------------
__global__ void k_bnstats(const float* __restrict__ h, float* __restrict__ gs) {
    int c = threadIdx.x & 127;
    int rl = threadIdx.x >> 7;
    float s = 0.f, q = 0.f;
    for (int r = blockIdx.x * 2 + rl; r < N_NODES; r += gridDim.x * 2) {
        float v = h[(size_t)r * F + c];
        s += v; q += v * v;
    }
    __shared__ float ls[256], lq[256];
    ls[threadIdx.x] = s; lq[threadIdx.x] = q;
    __syncthreads();
    if (rl == 0) {
        atomicAdd(&gs[c], ls[c] + ls[c + 128]);
        atomicAdd(&gs[128 + c], lq[c] + lq[c + 128]);
    }
}

// ---------------- fused BN-apply + GEMM: [y|z] = bn(h) @ [Wr0|Wr1|Wroot] ----------------
// Block = 64-row strip x all 384 cols, 512 threads. A staged once; B staged
// in LDS in 3 chunks of 128 cols. Swapped-operand MFMA (D^T): per lane the
// 4 acc regs are 4 consecutive n at fixed m -> 8B y-stores / 8B z-stores (bf16).
__launch_bounds__(512)
__global__ void k_gemm(const float* __restrict__ h, const float* __restrict__ gs,
                       const bf16* __restrict__ Bt, const float* __restrict__ bias,
                       bf16* __restrict__ y, bf16* __restrict__ z) {
    __shared__ bf16 As[64 * 136];    // 17.4 KB
    __shared__ bf16 Bs[128 * 136];   // 34.8 KB
    int t = threadIdx.x;
    int m0 = blockIdx.x * 64;
    // per-thread BN constants for its 4 fixed columns
    int c4 = (t & 31) * 4;
    float mu[4], rs[4];
    for (int c = 0; c < 4; c++) {
        float mm = gs[c4 + c] * (1.0f / N_NODES);
        float qq = gs[128 + c4 + c] * (1.0f / N_NODES);
        mu[c] = mm;
        rs[c] = rsqrtf(qq - mm * mm + BN_EPS);
    }
    // stage A (BN applied, f32 -> bf16)
    int r0 = t >> 5;  // 0..15
    for (int it = 0; it < 4; it++) {
        int row = r0 + it * 16;
        int m = m0 + row;
        float4 v = {0.f, 0.f, 0.f, 0.f};
        if (m < N_NODES) v = *(const float4*)(h + (size_t)m * F + c4);
        bf16 o[4];
        o[0] = __float2bfloat16((v.x - mu[0]) * rs[0] + BETA);
        o[1] = __float2bfloat16((v.y - mu[1]) * rs[1] + BETA);
        o[2] = __float2bfloat16((v.z - mu[2]) * rs[2] + BETA);
        o[3] = __float2bfloat16((v.w - mu[3]) * rs[3] + BETA);
        *(double*)(As + row * 136 + c4) = *(const double*)o;
    }
    __syncthreads();
    int w = t >> 6;
    int lane = t & 63;
    int msub = w & 3;   // m-subtile 0..3
    int nh = w >> 2;    // n-half of chunk 0..1
    int lm = lane & 15;
    int lq = lane >> 4;
    short8 a[4];
    for (int ki = 0; ki < 4; ki++)
        a[ki] = *(const short8*)(As + (msub * 16 + lm) * 136 + ki * 32 + lq * 8);
    int m = m0 + msub * 16 + lm;
    for (int ci = 0; ci < 3; ci++) {
        __syncthreads();  // previous chunk's Bs readers done
        // stage Bs: Bt rows [ci*128, ci*128+128), fully coalesced
        {
            const bf16* bsrc = Bt + (size_t)ci * 128 * F;
            for (int rr = 0; rr < 4; rr++) {
                int idx = rr * 512 + t;   // 0..2047
                int row = idx >> 4;       // 0..127
                int kc = idx & 15;        // 16-B chunk within row
                short8 v = *(const short8*)(bsrc + row * F + kc * 8);
                *(short8*)(Bs + row * 136 + kc * 8) = v;
            }
        }
        __syncthreads();
        for (int tt = 0; tt < 4; tt++) {
            int nt = nh * 4 + tt;   // n-tile within chunk, 0..7
            short8 b[4];
            for (int ki = 0; ki < 4; ki++)
                b[ki] = *(const short8*)(Bs + (nt * 16 + lm) * 136 + ki * 32 + lq * 8);
            floatx4 acc = {0.f, 0.f, 0.f, 0.f};
            for (int ki = 0; ki < 4; ki++)
                acc = __builtin_amdgcn_mfma_f32_16x16x32_bf16(b[ki], a[ki], acc, 0, 0, 0);
            // D^T: lane holds C[m][n0+reg], n0 = ci*128 + nt*16 + lq*4
            int n0 = ci * 128 + nt * 16 + lq * 4;
            if (m < N_NODES) {
                if (ci < 2) {
                    union { bf16 o[4]; double d; } u;
                    u.o[0] = __float2bfloat16(acc[0]);
                    u.o[1] = __float2bfloat16(acc[1]);
                    u.o[2] = __float2bfloat16(acc[2]);
                    u.o[3] = __float2bfloat16(acc[3]);
                    *(double*)(y + (size_t)m * 256 + n0) = u.d;
                } else {
                    float4 bv = *(const float4*)(bias + (n0 - 256));
                    union { bf16 o[4]; double d; } u;
                    u.o[0] = __float2bfloat16(acc[0] + bv.x);
                    u.o[1] = __float2bfloat16(acc[1] + bv.y);
                    u.o[2] = __float2bfloat16(acc[2] + bv.z);
                    u.o[3] = __float2bfloat16(acc[3] + bv.w);
                    *(double*)(z + (size_t)m * F + (n0 - 256)) = u.d;
                }
            }
        }
    }
}

// ---------------- per-(node,rel) pull aggregation + relu + residual ----------------
// 2 waves per node (one per relation) for 100k-wave gather concurrency.
// Inner loop is pure gather+add (inv applied once); partials combined via LDS.
__global__ void k_aggregate(const bf16* __restrict__ y, const bf16* __restrict__ z,
                            const int* __restrict__ cnt, const int* __restrict__ off,
                            const int* __restrict__ esrc,
                            float* __restrict__ h, float* __restrict__ outp, int layer) {
    __shared__ float pa[4][64];
    __shared__ float pb[4][64];
    int wv = threadIdx.x >> 6;        // wave in block 0..3
    int lane = threadIdx.x & 63;
    int wid2 = blockIdx.x * 4 + wv;   // 0..99999 (grid exact)
    int n = wid2 >> 1;
    int r = wid2 & 1;
    int f = lane * 2;
    int seg = n * R + r;
    int c = cnt[seg];
    int o = off[seg];
    float inv = (c > 0) ? 1.0f / (float)c : 0.f;
    const bf16* yb = y + (size_t)r * 128 + f;
    float sa[8], sb[8];
    #pragma unroll
    for (int k = 0; k < 8; k++) { sa[k] = 0.f; sb[k] = 0.f; }
    int i = 0;
    for (; i + 8 <= c; i += 8) {
        int sn[8];
        #pragma unroll
        for (int k = 0; k < 8; k++) sn[k] = esrc[o + i + k];
        __hip_bfloat162 p[8];
        #pragma unroll
        for (int k = 0; k < 8; k++)
            p[k] = *(const __hip_bfloat162*)(yb + (size_t)sn[k] * 256);
        #pragma unroll
        for (int k = 0; k < 8; k++) {
            sa[k] += __bfloat162float(p[k].x);
            sb[k] += __bfloat162float(p[k].y);
        }
    }
    if (i + 4 <= c) {
        int sn[4];
        #pragma unroll
        for (int k = 0; k < 4; k++) sn[k] = esrc[o + i + k];
        __hip_bfloat162 p[4];
        #pragma unroll
        for (int k = 0; k < 4; k++)
            p[k] = *(const __hip_bfloat162*)(yb + (size_t)sn[k] * 256);
        #pragma unroll
        for (int k = 0; k < 4; k++) {
            sa[k] += __bfloat162float(p[k].x);
            sb[k] += __bfloat162float(p[k].y);
        }
        i += 4;
    }
    for (; i < c; i++) {
        int sn = esrc[o + i];
        __hip_bfloat162 p = *(const __hip_bfloat162*)(yb + (size_t)sn * 256);
        sa[0] += __bfloat162float(p.x);
        sb[0] += __bfloat162float(p.y);
    }
    float px = (((sa[0] + sa[1]) + (sa[2] + sa[3])) + ((sa[4] + sa[5]) + (sa[6] + sa[7]))) * inv;
    float py = (((sb[0] + sb[1]) + (sb[2] + sb[3])) + ((sb[4] + sb[5]) + (sb[6] + sb[7]))) * inv;
    pa[wv][lane] = px;
    pb[wv][lane] = py;
    __syncthreads();
    if ((wv & 1) == 0) {
        float a0 = px + pa[wv + 1][lane];
        float a1 = py + pb[wv + 1][lane];
        __hip_bfloat162 zz = *(const __hip_bfloat162*)(z + (size_t)n * F + f);
        a0 += __bfloat162float(zz.x);
        a1 += __bfloat162float(zz.y);
        a0 = fmaxf(a0, 0.f);
        a1 = fmaxf(a1, 0.f);
        if (layer > 0) {
            float2 hp = *(const float2*)(h + (size_t)n * F + f);
            a0 += hp.x; a1 += hp.y;
        }
        float2 o2; o2.x = a0; o2.y = a1;
        *(float2*)(h + (size_t)n * F + f) = o2;
        if (outp) {
            float2 q2; q2.x = a0; q2.y = a1;
            *(float2*)(outp + (size_t)n * F + f) = q2;
        }
    }
}

extern "C" void kernel_launch(void* const* d_in, const int* in_sizes, int n_in,
                              void* d_out, int out_size, void* d_ws, size_t ws_size,
                              hipStream_t stream) {
    const float* x       = (const float*)d_in[0];
    const int*   eidx    = (const int*)d_in[1];
    const int*   etype   = (const int*)d_in[2];
    const float* W0_rel  = (const float*)d_in[3];
    const float* W0_root = (const float*)d_in[4];
    const float* b0      = (const float*)d_in[5];
    const float* Ws_rel  = (const float*)d_in[6];
    const float* Ws_root = (const float*)d_in[7];
    const float* bs      = (const float*)d_in[8];
    const int* src = eidx;
    const int* dst = eidx + N_EDGES;

    char* w = (char*)d_ws;
    float* h   = (float*)w; w += (size_t)N_NODES * F * 4;     // 25.6 MB
    bf16*  z   = (bf16*)w;  w += (size_t)N_NODES * F * 2;     // 12.8 MB
    bf16*  y   = (bf16*)w;  w += (size_t)N_NODES * 256 * 2;   // 25.6 MB
    bf16*  Bt  = (bf16*)w;  w += (size_t)NLAYER * NB * F * 2; // 384 KB
    int* cnt   = (int*)w;   w += (size_t)NSEG * 4;            // contiguous zero region:
    int* fill  = (int*)w;   w += (size_t)NSEG * 4;            //   cnt | fill | stats
    float* stats = (float*)w; w += (size_t)NLAYER * 256 * 4;
    int* off   = (int*)w;   w += (size_t)NSEG * 4;
    int* esrc  = (int*)w;   w += (size_t)N_EDGES * 4;
    int* bsum  = (int*)w;   w += 128 * 4;                     // total ~68 MB

    hipMemsetAsync(cnt, 0, (size_t)NSEG * 4 * 2 + (size_t)NLAYER * 256 * 4, stream);
    k_wt<<<(NLAYER * NB * F + 255) / 256, 256, 0, stream>>>(W0_rel, W0_root, Ws_rel, Ws_root, Bt);
    k_count<<<(N_EDGES + 255) / 256, 256, 0, stream>>>(dst, etype, cnt);
    k_scan1<<<NSCB, 1024, 0, stream>>>(cnt, off, bsum);
    k_scan2<<<1, 128, 0, stream>>>(bsum);
    k_scan3<<<NSCB, 1024, 0, stream>>>(off, bsum);
    k_fill<<<(N_EDGES + 255) / 256, 256, 0, stream>>>(src, dst, etype, off, fill, esrc);

    for (int l = 0; l < NLAYER; l++) {
        float* gs = stats + l * 256;
        const float* bias = (l == 0) ? b0 : (bs + (size_t)(l - 1) * F);
        const float* hin = (l == 0) ? x : h;
        k_bnstats<<<512, 256, 0, stream>>>(hin, gs);
        k_gemm<<<(N_NODES + 63) / 64, 512, 0, stream>>>(
            hin, gs, Bt + (size_t)l * NB * F, bias, y, z);
        k_aggregate<<<NSEG / 4, 256, 0, stream>>>(
            y, z, cnt, off, esrc, h, (l == 3) ? (float*)d_out : nullptr, l);
    }
}